// Round 5
// baseline (52.244 us; speedup 1.0000x reference)
//
#include <hip/hip_runtime.h>
#include <hip/hip_bf16.h>

#define N_NODES 4096
#define F_DIM   512
#define U_DIM   64
#define H_HEADS 8
#define C_DIM   512   // H*U
#define LRELU_S 0.2f
#define MAXE    128   // mean degree 42, sd 6.4; P(E>128) ~ 1e-25
#define GEMM_BLOCKS 128  // (4096/128 m-blocks) x (512/128 col-blocks)

typedef __attribute__((ext_vector_type(8))) short bf16x8;
typedef __attribute__((ext_vector_type(4))) float f32x4;

__device__ inline unsigned short f2bf(float f) {
  union { float f; unsigned u; } v; v.f = f;
  unsigned r = v.u + 0x7FFFu + ((v.u >> 16) & 1u);  // RTNE
  return (unsigned short)(r >> 16);
}
__device__ inline float bf2f(unsigned short b) {
  union { unsigned u; float f; } v; v.u = ((unsigned)b) << 16;
  return v.f;
}

// ---------------------------------------------------------------------------
// front_kernel:
//  blocks [0, GEMM_BLOCKS): h = X@W tile 128(M) x 128(N = 2 heads), bf16 MFMA,
//    4 waves (2x2), wave tile 64x64; fused in-register f_self/f_neigh epilogue.
//    head-pair = blockIdx&3 -> same W slab stays on the same XCDs' L2.
//  blocks [GEMM_BLOCKS, +N): scan one A row each into CSR (deg, nbr).
//  The HBM-bound scan overlaps the compute-bound GEMM in one dispatch.
// ---------------------------------------------------------------------------
__global__ __launch_bounds__(256) void front_kernel(
    const float* __restrict__ X, const float* __restrict__ W,
    const float* __restrict__ A, const float* __restrict__ a_self,
    const float* __restrict__ a_neigh, unsigned short* __restrict__ hb,
    float* __restrict__ fs, float* __restrict__ fn, int* __restrict__ deg,
    unsigned short* __restrict__ nbr) {
  __shared__ unsigned short As[128][40];  // [m][k], stride 80 B (16B-aligned)
  __shared__ unsigned short Bs[128][40];  // [c][k] (B transposed)
  __shared__ int wsum[4];

  const int t    = threadIdx.x;
  const int lane = t & 63;
  const int w    = t >> 6;

  if ((int)blockIdx.x < GEMM_BLOCKS) {
    // ---------------- GEMM branch ----------------
    const int hp   = blockIdx.x & 3;   // head-pair (XCD affinity via %8 rr)
    const int mblk = blockIdx.x >> 2;  // 0..31
    const int m0   = mblk * 128;
    const int n0   = hp * 128;         // flat col base (= head hp*2)

    const int wr = w >> 1, wc = w & 1;  // wave grid 2x2, wave tile 64x64

    // A staging map: thread -> (row, k-half)
    const int arow = t >> 1;
    const int akq  = (t & 1) * 16;
    // B staging map: thread -> (col 0..127, k-half)
    const int bcl = t & 127;
    const int bkq = (t >> 7) * 16;
    const int bgc = n0 + bcl;  // global flat col
    const float* wcol = W + ((size_t)(bgc >> 6) * F_DIM) * U_DIM + (bgc & 63);

    f32x4 acc[4][4] = {};

    for (int k0 = 0; k0 < F_DIM; k0 += 32) {
      // stage A: 128x32 fp32 -> bf16
      {
        const float* src = X + (size_t)(m0 + arow) * F_DIM + k0 + akq;
        float4 f0 = ((const float4*)src)[0];
        float4 f1 = ((const float4*)src)[1];
        float4 f2 = ((const float4*)src)[2];
        float4 f3 = ((const float4*)src)[3];
        bf16x8 u0 = {(short)f2bf(f0.x), (short)f2bf(f0.y), (short)f2bf(f0.z),
                     (short)f2bf(f0.w), (short)f2bf(f1.x), (short)f2bf(f1.y),
                     (short)f2bf(f1.z), (short)f2bf(f1.w)};
        bf16x8 u1 = {(short)f2bf(f2.x), (short)f2bf(f2.y), (short)f2bf(f2.z),
                     (short)f2bf(f2.w), (short)f2bf(f3.x), (short)f2bf(f3.y),
                     (short)f2bf(f3.z), (short)f2bf(f3.w)};
        *(bf16x8*)&As[arow][akq]     = u0;
        *(bf16x8*)&As[arow][akq + 8] = u1;
      }
      // stage B transposed: Bs[c][k] = W[c>>6][k][c&63]
      {
        float bv[16];
#pragma unroll
        for (int j = 0; j < 16; ++j)
          bv[j] = wcol[(size_t)(k0 + bkq + j) * U_DIM];
        bf16x8 w0 = {(short)f2bf(bv[0]), (short)f2bf(bv[1]), (short)f2bf(bv[2]),
                     (short)f2bf(bv[3]), (short)f2bf(bv[4]), (short)f2bf(bv[5]),
                     (short)f2bf(bv[6]), (short)f2bf(bv[7])};
        bf16x8 w1 = {(short)f2bf(bv[8]),  (short)f2bf(bv[9]),
                     (short)f2bf(bv[10]), (short)f2bf(bv[11]),
                     (short)f2bf(bv[12]), (short)f2bf(bv[13]),
                     (short)f2bf(bv[14]), (short)f2bf(bv[15])};
        *(bf16x8*)&Bs[bcl][bkq]     = w0;
        *(bf16x8*)&Bs[bcl][bkq + 8] = w1;
      }
      __syncthreads();

      const int r  = lane & 15;
      const int ko = (lane >> 4) * 8;
      bf16x8 af[4], bfr[4];
#pragma unroll
      for (int mi = 0; mi < 4; ++mi)
        af[mi] = *(const bf16x8*)&As[wr * 64 + mi * 16 + r][ko];
#pragma unroll
      for (int ni = 0; ni < 4; ++ni)
        bfr[ni] = *(const bf16x8*)&Bs[wc * 64 + ni * 16 + r][ko];
#pragma unroll
      for (int mi = 0; mi < 4; ++mi)
#pragma unroll
        for (int ni = 0; ni < 4; ++ni)
          acc[mi][ni] = __builtin_amdgcn_mfma_f32_16x16x32_bf16(
              af[mi], bfr[ni], acc[mi][ni], 0, 0, 0);
      __syncthreads();
    }

    // ---- epilogue 1: hb write (C/D map: col=lane&15, row=(lane>>4)*4+reg)
    const int head = hp * 2 + wc;  // this wave's single head
#pragma unroll
    for (int mi = 0; mi < 4; ++mi) {
#pragma unroll
      for (int ni = 0; ni < 4; ++ni) {
        const int row = m0 + wr * 64 + mi * 16 + (lane >> 4) * 4;
        const int col = n0 + wc * 64 + ni * 16 + (lane & 15);
#pragma unroll
        for (int reg = 0; reg < 4; ++reg)
          hb[(size_t)(row + reg) * C_DIM + col] = f2bf(acc[mi][ni][reg]);
      }
    }

    // ---- epilogue 2: fused logits from fp32 accumulators.
    // f[row] = sum_col acc * a[col]; 16-lane column group holds all 64 cols
    // (4 ni x lane&15). shfl_xor {1,2,4,8} reduces within the group.
    {
      float asv[4], anv[4];
#pragma unroll
      for (int ni = 0; ni < 4; ++ni) {
        const int u = wc * 64 + ni * 16 + (lane & 15) - wc * 64;  // local u
        asv[ni] = a_self[head * U_DIM + ni * 16 + (lane & 15)];
        anv[ni] = a_neigh[head * U_DIM + ni * 16 + (lane & 15)];
        (void)u;
      }
#pragma unroll
      for (int mi = 0; mi < 4; ++mi) {
#pragma unroll
        for (int reg = 0; reg < 4; ++reg) {
          float ps = 0.f, pn = 0.f;
#pragma unroll
          for (int ni = 0; ni < 4; ++ni) {
            ps += acc[mi][ni][reg] * asv[ni];
            pn += acc[mi][ni][reg] * anv[ni];
          }
#pragma unroll
          for (int off = 1; off < 16; off <<= 1) {
            ps += __shfl_xor(ps, off);
            pn += __shfl_xor(pn, off);
          }
          if ((lane & 15) == 0) {
            const int row = m0 + wr * 64 + mi * 16 + (lane >> 4) * 4 + reg;
            fs[head * N_NODES + row] = ps;
            fn[head * N_NODES + row] = pn;
          }
        }
      }
    }
  } else {
    // ---------------- scan branch: node i -> CSR ----------------
    const int i = (int)blockIdx.x - GEMM_BLOCKS;
    const float* Arow = A + (size_t)i * N_NODES;
    const int base = t * 16;
    float av[16];
#pragma unroll
    for (int q = 0; q < 4; ++q) {
      float4 x = *(const float4*)(Arow + base + q * 4);
      av[q * 4 + 0] = x.x;
      av[q * 4 + 1] = x.y;
      av[q * 4 + 2] = x.z;
      av[q * 4 + 3] = x.w;
    }
    int c = 0;
#pragma unroll
    for (int q = 0; q < 16; ++q) c += (av[q] != 0.0f) ? 1 : 0;

    int psum = c;
#pragma unroll
    for (int off = 1; off < 64; off <<= 1) {
      int v = __shfl_up(psum, off);
      if (lane >= off) psum += v;
    }
    if (lane == 63) wsum[w] = psum;
    __syncthreads();
    int woff = 0;
#pragma unroll
    for (int k = 0; k < 4; ++k)
      if (k < w) woff += wsum[k];
    int E = wsum[0] + wsum[1] + wsum[2] + wsum[3];
    if (E > MAXE) E = MAXE;  // P ~ 1e-25, safety only

    int pos = woff + psum - c;  // exclusive prefix
#pragma unroll
    for (int q = 0; q < 16; ++q) {
      if (av[q] != 0.0f) {
        if (pos < MAXE) nbr[(size_t)i * MAXE + pos] = (unsigned short)(base + q);
        ++pos;
      }
    }
    if (t == 0) deg[i] = E;
  }
}

// ---------------------------------------------------------------------------
// attn_kernel: 2 nodes per block, 2 waves per node. ONE barrier total:
// each wave aggregates exactly the heads whose softmax it computed, so only
// the edge-list handoff needs a block sync. Agg gathers dwordx2 (4 bf16) per
// lane per edge; 1/sum folded into the epilogue.
// ---------------------------------------------------------------------------
__global__ __launch_bounds__(256) void attn_kernel(
    const unsigned short* __restrict__ hb, const float* __restrict__ fs,
    const float* __restrict__ fn, const float* __restrict__ bias,
    const int* __restrict__ deg, const unsigned short* __restrict__ nbr,
    float* __restrict__ out) {
  __shared__ int   eidx[2][MAXE];
  __shared__ float p[2][H_HEADS][MAXE];  // 8 KB
  __shared__ float sinv[2][H_HEADS];

  const int t    = threadIdx.x;
  const int lane = t & 63;
  const int w    = t >> 6;
  const int nd   = w >> 1;  // node half 0/1
  const int wn   = w & 1;   // wave within node 0/1
  const int i    = blockIdx.x * 2 + nd;
  const int E    = deg[i];

  {
    const int e = wn * 64 + lane;
    if (e < E) eidx[nd][e] = (int)nbr[(size_t)i * MAXE + e];
  }
  __syncthreads();  // the only barrier

  // softmax: wave handles heads wn*4 .. wn*4+3 of its node
#pragma unroll
  for (int hh = 0; hh < 4; ++hh) {
    const int h = wn * 4 + hh;
    const float fsi = fs[h * N_NODES + i];
    const float* fnh = fn + h * N_NODES;
    float lmax = -1e30f;
    for (int e = lane; e < E; e += 64) {
      float sc = fsi + fnh[eidx[nd][e]];
      sc = (sc > 0.f) ? sc : LRELU_S * sc;
      p[nd][h][e] = sc;
      lmax = fmaxf(lmax, sc);
    }
#pragma unroll
    for (int off = 32; off > 0; off >>= 1)
      lmax = fmaxf(lmax, __shfl_xor(lmax, off));
    float lsum = 0.f;
    for (int e = lane; e < E; e += 64) {
      float pe = __expf(p[nd][h][e] - lmax);
      p[nd][h][e] = pe;
      lsum += pe;
    }
#pragma unroll
    for (int off = 32; off > 0; off >>= 1) lsum += __shfl_xor(lsum, off);
    if (lane == 0) sinv[nd][h] = 1.0f / lsum;
  }
  // no barrier: agg below touches only this wave's own heads (wave-sync LDS)

  // aggregation: lane covers 4 cols cbase..cbase+3 (one head)
  const int cbase = wn * 256 + 4 * lane;
  const int h = wn * 4 + (lane >> 4);
  const float* ph = p[nd][h];
  float a0 = 0.f, a1 = 0.f, a2 = 0.f, a3 = 0.f;
#pragma unroll 4
  for (int e = 0; e < E; ++e) {
    const unsigned short* hp_ = hb + (size_t)eidx[nd][e] * C_DIM + cbase;
    uint2 v = *(const uint2*)hp_;
    float pe = ph[e];
    a0 += pe * bf2f((unsigned short)(v.x & 0xFFFFu));
    a1 += pe * bf2f((unsigned short)(v.x >> 16));
    a2 += pe * bf2f((unsigned short)(v.y & 0xFFFFu));
    a3 += pe * bf2f((unsigned short)(v.y >> 16));
  }
  const float inv = sinv[nd][h];
  float4 bv = *(const float4*)(bias + cbase);
  float4 o;
  o.x = fmaxf(a0 * inv + bv.x, 0.f);
  o.y = fmaxf(a1 * inv + bv.y, 0.f);
  o.z = fmaxf(a2 * inv + bv.z, 0.f);
  o.w = fmaxf(a3 * inv + bv.w, 0.f);
  *(float4*)(out + (size_t)i * C_DIM + cbase) = o;
}

// ---------------------------------------------------------------------------
extern "C" void kernel_launch(void* const* d_in, const int* in_sizes, int n_in,
                              void* d_out, int out_size, void* d_ws,
                              size_t ws_size, hipStream_t stream) {
  const float* X       = (const float*)d_in[0];
  // d_in[1] = out_indices (unused: final_layer=False returns all nodes)
  const float* A       = (const float*)d_in[2];
  const float* W       = (const float*)d_in[3];
  const float* a_self  = (const float*)d_in[4];
  const float* a_neigh = (const float*)d_in[5];
  const float* bias    = (const float*)d_in[6];
  float* out = (float*)d_out;

  unsigned short* hb = (unsigned short*)d_ws;               // N*C bf16 (4 MB)
  float* fs = (float*)(hb + (size_t)N_NODES * C_DIM);       // H*N f32
  float* fn = fs + (size_t)H_HEADS * N_NODES;               // H*N f32
  int* deg  = (int*)(fn + (size_t)H_HEADS * N_NODES);       // N int
  unsigned short* nbr = (unsigned short*)(deg + N_NODES);   // N*MAXE ushort

  front_kernel<<<GEMM_BLOCKS + N_NODES, 256, 0, stream>>>(
      X, W, A, a_self, a_neigh, hb, fs, fn, deg, nbr);

  attn_kernel<<<N_NODES / 2, 256, 0, stream>>>(hb, fs, fn, bias, deg, nbr, out);
}

// Round 6
// 40.447 us; speedup vs baseline: 1.2917x; 1.2917x over previous
//
#include <hip/hip_runtime.h>
#include <hip/hip_bf16.h>

#define N_NODES 4096
#define F_DIM   512
#define U_DIM   64
#define H_HEADS 8
#define C_DIM   512   // H*U
#define LRELU_S 0.2f
#define MAXE    128   // mean degree 42, sd 6.4; P(E>128) ~ 1e-25
#define GEMM_BLOCKS 512  // 64 m-blocks x 8 heads (proven round-4 shape)

typedef __attribute__((ext_vector_type(8))) short bf16x8;
typedef __attribute__((ext_vector_type(4))) float f32x4;

__device__ inline unsigned short f2bf(float f) {
  union { float f; unsigned u; } v; v.f = f;
  unsigned r = v.u + 0x7FFFu + ((v.u >> 16) & 1u);  // RTNE
  return (unsigned short)(r >> 16);
}
__device__ inline float bf2f(unsigned short b) {
  union { unsigned u; float f; } v; v.u = ((unsigned)b) << 16;
  return v.f;
}

// ---------------------------------------------------------------------------
// front_kernel: blocks [0, GEMM_BLOCKS): h = X@W (bf16 MFMA, tile 64x64,
// 4 waves of 32x32) + fused logits epilogue writing TRANSPOSED fsT/fnT
// ([node][head] layout -> attn reads all 8 head-logits in one 32 B load).
// blocks [GEMM_BLOCKS, +N): coalesced scan of one A row each into CSR.
// ---------------------------------------------------------------------------
__global__ __launch_bounds__(256) void front_kernel(
    const float* __restrict__ X, const float* __restrict__ W,
    const float* __restrict__ A, const float* __restrict__ a_self,
    const float* __restrict__ a_neigh, unsigned short* __restrict__ hb,
    float* __restrict__ fsT, float* __restrict__ fnT, int* __restrict__ deg,
    unsigned short* __restrict__ nbr) {
  __shared__ unsigned short As[64][72];  // +8 pad: 2-way bank alias only
  __shared__ unsigned short Bs[64][72];
  __shared__ int wsum[4];

  const int t    = threadIdx.x;
  const int lane = t & 63;
  const int w    = t >> 6;

  if ((int)blockIdx.x < GEMM_BLOCKS) {
    // ---------------- GEMM branch ----------------
    const int mblk = blockIdx.x & 63;
    const int head = blockIdx.x >> 6;
    const int m0   = mblk * 64;
    const float* Wh = W + (size_t)head * F_DIM * U_DIM;

    const int wr = w >> 1, wc = w & 1;   // wave grid 2x2, wave tile 32x32
    const int arow = t >> 2;             // A-stage row 0..63
    const int akc  = (t & 3) * 16;       // A-stage k offset
    const int bu   = t & 63;             // B-stage u
    const int bjc  = (t >> 6) * 16;      // B-stage k chunk

    f32x4 acc[2][2] = {};

    for (int k0 = 0; k0 < F_DIM; k0 += 64) {
      // stage A: 64x64 fp32 -> bf16, As[m][k]
      {
        const float* src = X + (size_t)(m0 + arow) * F_DIM + k0 + akc;
        float4 f0 = ((const float4*)src)[0];
        float4 f1 = ((const float4*)src)[1];
        float4 f2 = ((const float4*)src)[2];
        float4 f3 = ((const float4*)src)[3];
        bf16x8 u0 = {(short)f2bf(f0.x), (short)f2bf(f0.y), (short)f2bf(f0.z),
                     (short)f2bf(f0.w), (short)f2bf(f1.x), (short)f2bf(f1.y),
                     (short)f2bf(f1.z), (short)f2bf(f1.w)};
        bf16x8 u1 = {(short)f2bf(f2.x), (short)f2bf(f2.y), (short)f2bf(f2.z),
                     (short)f2bf(f2.w), (short)f2bf(f3.x), (short)f2bf(f3.y),
                     (short)f2bf(f3.z), (short)f2bf(f3.w)};
        *(bf16x8*)&As[arow][akc]     = u0;
        *(bf16x8*)&As[arow][akc + 8] = u1;
      }
      // stage B transposed: Bs[u][k] = W[head][k][u]
      {
        float bv[16];
#pragma unroll
        for (int j = 0; j < 16; ++j)
          bv[j] = Wh[(size_t)(k0 + bjc + j) * U_DIM + bu];
        bf16x8 w0 = {(short)f2bf(bv[0]), (short)f2bf(bv[1]), (short)f2bf(bv[2]),
                     (short)f2bf(bv[3]), (short)f2bf(bv[4]), (short)f2bf(bv[5]),
                     (short)f2bf(bv[6]), (short)f2bf(bv[7])};
        bf16x8 w1 = {(short)f2bf(bv[8]),  (short)f2bf(bv[9]),
                     (short)f2bf(bv[10]), (short)f2bf(bv[11]),
                     (short)f2bf(bv[12]), (short)f2bf(bv[13]),
                     (short)f2bf(bv[14]), (short)f2bf(bv[15])};
        *(bf16x8*)&Bs[bu][bjc]     = w0;
        *(bf16x8*)&Bs[bu][bjc + 8] = w1;
      }
      __syncthreads();

      const int r  = lane & 15;
      const int ko = (lane >> 4) * 8;
#pragma unroll
      for (int kk = 0; kk < 2; ++kk) {
        bf16x8 af0 = *(const bf16x8*)&As[wr * 32 + r][kk * 32 + ko];
        bf16x8 af1 = *(const bf16x8*)&As[wr * 32 + 16 + r][kk * 32 + ko];
        bf16x8 bf0 = *(const bf16x8*)&Bs[wc * 32 + r][kk * 32 + ko];
        bf16x8 bf1 = *(const bf16x8*)&Bs[wc * 32 + 16 + r][kk * 32 + ko];
        acc[0][0] = __builtin_amdgcn_mfma_f32_16x16x32_bf16(af0, bf0, acc[0][0], 0, 0, 0);
        acc[0][1] = __builtin_amdgcn_mfma_f32_16x16x32_bf16(af0, bf1, acc[0][1], 0, 0, 0);
        acc[1][0] = __builtin_amdgcn_mfma_f32_16x16x32_bf16(af1, bf0, acc[1][0], 0, 0, 0);
        acc[1][1] = __builtin_amdgcn_mfma_f32_16x16x32_bf16(af1, bf1, acc[1][1], 0, 0, 0);
      }
      __syncthreads();
    }

    // epilogue: write hb (global) + stash bf16 h-tile into As for logits
#pragma unroll
    for (int mi = 0; mi < 2; ++mi) {
#pragma unroll
      for (int ni = 0; ni < 2; ++ni) {
        const int rb = wr * 32 + mi * 16 + (lane >> 4) * 4;  // local row base
        const int cl = wc * 32 + ni * 16 + (lane & 15);      // local col
#pragma unroll
        for (int reg = 0; reg < 4; ++reg) {
          unsigned short hv = f2bf(acc[mi][ni][reg]);
          hb[(size_t)(m0 + rb + reg) * C_DIM + head * U_DIM + cl] = hv;
          As[rb + reg][cl] = hv;
        }
      }
    }
    __syncthreads();
    // fused logits: t<64 -> f_self row t; t in [64,128) -> f_neigh row t-64.
    // TRANSPOSED store: f*T[node*H + head].
    if (t < 128) {
      const int r = t & 63;
      const float* avec = (t >= 64) ? a_neigh + head * U_DIM
                                    : a_self + head * U_DIM;
      float s = 0.f;
#pragma unroll
      for (int u = 0; u < 64; ++u) s += bf2f(As[r][u]) * avec[u];
      float* dst = (t >= 64) ? fnT : fsT;
      dst[(size_t)(m0 + r) * H_HEADS + head] = s;
    }
  } else {
    // ---------------- scan branch: node i -> CSR, coalesced ----------------
    // Thread t owns elements {4t + q*1024 + j}: each float4 load is
    // unit-stride across the wave (16 cache lines/instr, not 64).
    const int i = (int)blockIdx.x - GEMM_BLOCKS;
    const float* Arow = A + (size_t)i * N_NODES;
    float av[4][4];
#pragma unroll
    for (int q = 0; q < 4; ++q) {
      float4 x = *(const float4*)(Arow + 4 * t + q * 1024);
      av[q][0] = x.x; av[q][1] = x.y; av[q][2] = x.z; av[q][3] = x.w;
    }
    int c = 0;
#pragma unroll
    for (int q = 0; q < 4; ++q)
#pragma unroll
      for (int j = 0; j < 4; ++j) c += (av[q][j] != 0.0f) ? 1 : 0;

    int psum = c;
#pragma unroll
    for (int off = 1; off < 64; off <<= 1) {
      int v = __shfl_up(psum, off);
      if (lane >= off) psum += v;
    }
    if (lane == 63) wsum[w] = psum;
    __syncthreads();
    int woff = 0;
#pragma unroll
    for (int k = 0; k < 4; ++k)
      if (k < w) woff += wsum[k];
    int E = wsum[0] + wsum[1] + wsum[2] + wsum[3];
    if (E > MAXE) E = MAXE;  // P ~ 1e-25, safety only

    int pos = woff + psum - c;  // exclusive prefix (thread-major order)
#pragma unroll
    for (int q = 0; q < 4; ++q) {
#pragma unroll
      for (int j = 0; j < 4; ++j) {
        if (av[q][j] != 0.0f) {
          if (pos < MAXE)
            nbr[(size_t)i * MAXE + pos] = (unsigned short)(4 * t + q * 1024 + j);
          ++pos;
        }
      }
    }
    if (t == 0) deg[i] = E;
  }
}

// ---------------------------------------------------------------------------
// attn_kernel: 4 nodes per block, ONE wave per node (all 8 heads).
// Softmax: one 32 B fnT gather per edge covers all heads; shfl reductions.
// Agg: lane owns 8 cols; one uint4 (16 B) gather per edge per lane -> the
// wave reads the full 1 KB h-row in a single instruction per edge.
// One __syncthreads total (cross-lane LDS visibility for p/eidx).
// ---------------------------------------------------------------------------
__global__ __launch_bounds__(256) void attn_kernel(
    const unsigned short* __restrict__ hb, const float* __restrict__ fsT,
    const float* __restrict__ fnT, const float* __restrict__ bias,
    const int* __restrict__ deg, const unsigned short* __restrict__ nbr,
    float* __restrict__ out) {
  __shared__ int   eidx[4][MAXE];
  __shared__ float p[4][MAXE][9];  // pad 9: conflict-free read by 8 h-groups

  const int t    = threadIdx.x;
  const int lane = t & 63;
  const int w    = t >> 6;            // node slot in block
  const int i    = blockIdx.x * 4 + w;
  const int E    = deg[i];

  // self logits (all lanes same 32 B -> broadcast)
  float fsv[8];
  {
    float4 a = *(const float4*)(fsT + (size_t)i * H_HEADS);
    float4 b = *(const float4*)(fsT + (size_t)i * H_HEADS + 4);
    fsv[0]=a.x; fsv[1]=a.y; fsv[2]=a.z; fsv[3]=a.w;
    fsv[4]=b.x; fsv[5]=b.y; fsv[6]=b.z; fsv[7]=b.w;
  }

  // pass 1: edge load + raw scores to LDS + per-head local max
  float pmax[8];
#pragma unroll
  for (int h = 0; h < 8; ++h) pmax[h] = -1e30f;
  for (int e = lane; e < E; e += 64) {
    const int j = (int)nbr[(size_t)i * MAXE + e];
    eidx[w][e] = j;
    float4 a = *(const float4*)(fnT + (size_t)j * H_HEADS);
    float4 b = *(const float4*)(fnT + (size_t)j * H_HEADS + 4);
    float fnv[8] = {a.x, a.y, a.z, a.w, b.x, b.y, b.z, b.w};
#pragma unroll
    for (int h = 0; h < 8; ++h) {
      float sc = fsv[h] + fnv[h];
      sc = (sc > 0.f) ? sc : LRELU_S * sc;
      p[w][e][h] = sc;
      pmax[h] = fmaxf(pmax[h], sc);
    }
  }
#pragma unroll
  for (int h = 0; h < 8; ++h)
#pragma unroll
    for (int off = 32; off > 0; off >>= 1)
      pmax[h] = fmaxf(pmax[h], __shfl_xor(pmax[h], off));

  // pass 2: exp + per-head sum (own-lane LDS RAW only)
  float psum[8] = {};
  for (int e = lane; e < E; e += 64) {
#pragma unroll
    for (int h = 0; h < 8; ++h) {
      float ex = __expf(p[w][e][h] - pmax[h]);
      p[w][e][h] = ex;
      psum[h] += ex;
    }
  }
#pragma unroll
  for (int h = 0; h < 8; ++h)
#pragma unroll
    for (int off = 32; off > 0; off >>= 1) psum[h] += __shfl_xor(psum[h], off);

  __syncthreads();  // p/eidx cross-lane visibility

  // aggregation: lane owns cols 8*lane..8*lane+7 (head hl = lane>>3)
  const int cbase = 8 * lane;
  const int hl = lane >> 3;
  float acc[8] = {};
  for (int e = 0; e < E; ++e) {
    const int j = eidx[w][e];                 // broadcast LDS read
    uint4 v = *(const uint4*)(hb + (size_t)j * C_DIM + cbase);
    const float pe = p[w][e][hl];             // conflict-free LDS read
    acc[0] += pe * bf2f((unsigned short)(v.x & 0xFFFFu));
    acc[1] += pe * bf2f((unsigned short)(v.x >> 16));
    acc[2] += pe * bf2f((unsigned short)(v.y & 0xFFFFu));
    acc[3] += pe * bf2f((unsigned short)(v.y >> 16));
    acc[4] += pe * bf2f((unsigned short)(v.z & 0xFFFFu));
    acc[5] += pe * bf2f((unsigned short)(v.z >> 16));
    acc[6] += pe * bf2f((unsigned short)(v.w & 0xFFFFu));
    acc[7] += pe * bf2f((unsigned short)(v.w >> 16));
  }
  // select 1/sum for this lane's head without runtime reg-array indexing
  float sum = psum[0];
#pragma unroll
  for (int h = 1; h < 8; ++h)
    if (hl == h) sum = psum[h];
  const float inv = 1.0f / sum;

  float4 b0 = *(const float4*)(bias + cbase);
  float4 b1 = *(const float4*)(bias + cbase + 4);
  float4 o0, o1;
  o0.x = fmaxf(acc[0] * inv + b0.x, 0.f);
  o0.y = fmaxf(acc[1] * inv + b0.y, 0.f);
  o0.z = fmaxf(acc[2] * inv + b0.z, 0.f);
  o0.w = fmaxf(acc[3] * inv + b0.w, 0.f);
  o1.x = fmaxf(acc[4] * inv + b1.x, 0.f);
  o1.y = fmaxf(acc[5] * inv + b1.y, 0.f);
  o1.z = fmaxf(acc[6] * inv + b1.z, 0.f);
  o1.w = fmaxf(acc[7] * inv + b1.w, 0.f);
  *(float4*)(out + (size_t)i * C_DIM + cbase)     = o0;
  *(float4*)(out + (size_t)i * C_DIM + cbase + 4) = o1;
}

// ---------------------------------------------------------------------------
extern "C" void kernel_launch(void* const* d_in, const int* in_sizes, int n_in,
                              void* d_out, int out_size, void* d_ws,
                              size_t ws_size, hipStream_t stream) {
  const float* X       = (const float*)d_in[0];
  // d_in[1] = out_indices (unused: final_layer=False returns all nodes)
  const float* A       = (const float*)d_in[2];
  const float* W       = (const float*)d_in[3];
  const float* a_self  = (const float*)d_in[4];
  const float* a_neigh = (const float*)d_in[5];
  const float* bias    = (const float*)d_in[6];
  float* out = (float*)d_out;

  unsigned short* hb = (unsigned short*)d_ws;               // N*C bf16 (4 MB)
  float* fsT = (float*)(hb + (size_t)N_NODES * C_DIM);      // N*H f32
  float* fnT = fsT + (size_t)H_HEADS * N_NODES;             // N*H f32
  int* deg   = (int*)(fnT + (size_t)H_HEADS * N_NODES);     // N int
  unsigned short* nbr = (unsigned short*)(deg + N_NODES);   // N*MAXE ushort

  front_kernel<<<GEMM_BLOCKS + N_NODES, 256, 0, stream>>>(
      X, W, A, a_self, a_neigh, hb, fsT, fnT, deg, nbr);

  attn_kernel<<<N_NODES / 4, 256, 0, stream>>>(hb, fsT, fnT, bias, deg, nbr, out);
}